// Round 7
// baseline (296.498 us; speedup 1.0000x reference)
//
#include <hip/hip_runtime.h>
#include <hip/hip_bf16.h>

typedef float f32x4 __attribute__((ext_vector_type(4)));
typedef short s16x8 __attribute__((ext_vector_type(8)));
typedef unsigned long long ull;

#define NROWS 8192
#define MCOLS 8192
#define DIM   128
#define BI    32
#define NTILE 256   // MCOLS / 32

// ---- prep: per-row norm + bf16 convert for BOTH xi (scaled by beta) and xj ----
__global__ void prep_scale_both(const float* __restrict__ xi,
                                const float* __restrict__ xj,
                                const float* __restrict__ beta,
                                __hip_bfloat16* __restrict__ Qbf,
                                __hip_bfloat16* __restrict__ Kbf) {
    int gr = blockIdx.x * 4 + (threadIdx.x >> 6);
    int l = threadIdx.x & 63;
    const float* src;
    __hip_bfloat16* dst;
    int row;
    if (gr < NROWS) { row = gr;          src = xi; dst = Qbf; }
    else            { row = gr - NROWS;  src = xj; dst = Kbf; }
    const float* xr = src + (size_t)row * DIM;
    float x0 = xr[l], x1 = xr[l + 64];
    float ss = x0 * x0 + x1 * x1;
#pragma unroll
    for (int off = 32; off >= 1; off >>= 1) ss += __shfl_xor(ss, off);
    float s = 1.0f / sqrtf(ss);
    if (gr < NROWS) s *= beta[0];
    __hip_bfloat16* o = dst + (size_t)row * DIM;
    o[l]      = __float2bfloat16(x0 * s);
    o[l + 64] = __float2bfloat16(x1 * s);
}

// ---- prep: transpose xj -> Vt[d][j] bf16 (raw values) ----
__global__ void prep_vt(const float* __restrict__ xj, __hip_bfloat16* __restrict__ vt) {
    __shared__ float tile[64][65];
    int j0 = blockIdx.x * 64;
    int d0 = blockIdx.y * 64;
    int t = threadIdx.x; // 256
#pragma unroll
    for (int c = 0; c < 16; ++c) {
        int idx = t + 256 * c;
        int jr = idx >> 6, dc = idx & 63;
        tile[jr][dc] = xj[(size_t)(j0 + jr) * DIM + d0 + dc];
    }
    __syncthreads();
#pragma unroll
    for (int c = 0; c < 16; ++c) {
        int idx = t + 256 * c;
        int dr = idx >> 6, jc = idx & 63;
        vt[(size_t)(d0 + dr) * MCOLS + j0 + jc] = __float2bfloat16(tile[jc][dr]);
    }
}

// ---- pack adj -> bits, GRID-CONTIGUOUS stream (channel-balanced).
//      Window W (256 cols of one row): lane reads int4 at col 4*lane..4*lane+3.
//      Ballot-native layout: bm[W*4+k] bit l  <->  col 256W + 4l + k. ----
__global__ __launch_bounds__(256) void pack_adj7(const int* __restrict__ adj,
                                                 ull* __restrict__ bm) {
    const int lane = threadIdx.x & 63;
    const int gw = (int)((blockIdx.x * 256 + threadIdx.x) >> 6); // 0..8191
    const int4* base = (const int4*)adj;
#pragma unroll 2
    for (int s = 0; s < 32; ++s) {
        int win = gw + s * 8192;          // grid covers 8MB contiguous per step
        int4 a = base[(size_t)win * 64 + lane];
        ull b0 = __ballot(a.x != 0);
        ull b1 = __ballot(a.y != 0);
        ull b2 = __ballot(a.z != 0);
        ull b3 = __ballot(a.w != 0);
        if (lane < 4) {
            ull v = lane == 0 ? b0 : (lane == 1 ? b1 : (lane == 2 ? b2 : b3));
            bm[(size_t)win * 4 + lane] = v;
        }
    }
}

// ---- flash attention, MFMA-only kernel: mask bits + K/V all L2/L3-resident
//      (homogeneous latency -> counted vmcnt works); barrier-free main loop;
//      no max-tracking softmax (|score| <= beta < 1): p = adj ? exp(s) : 0 ----
__global__ __launch_bounds__(1024) void flash7(const __hip_bfloat16* __restrict__ Qbf,
                                               const __hip_bfloat16* __restrict__ Kbf,
                                               const __hip_bfloat16* __restrict__ Vt,
                                               const ull* __restrict__ bm,
                                               float* __restrict__ out) {
    __shared__ char smem[66048];
    __hip_bfloat16* Plds  = (__hip_bfloat16*)smem;     // [16 waves][16][40] = 20 KiB
    float*          Opart = (float*)smem;              // epilogue reuse: [8][16][128] = 64 KiB
    float*          Lpart = (float*)(smem + 65536);    // epilogue: [8][16]

    const int tid  = threadIdx.x;
    const int w    = tid >> 6;
    const int lane = tid & 63;
    const int g    = lane >> 4;
    const int ln   = lane & 15;
    const int rg   = w >> 3;   // 0..1 row group (16 rows)
    const int wj   = w & 7;    // 0..7 j slice (32 tiles each)
    const int i0   = blockIdx.x * BI;
    const int ri0  = i0 + rg * 16;

    s16x8 qf[4];
#pragma unroll
    for (int kt = 0; kt < 4; ++kt)
        qf[kt] = *(const s16x8*)(Qbf + (size_t)(ri0 + ln) * DIM + kt * 32 + g * 8);

    f32x4 zero = {0.f, 0.f, 0.f, 0.f};
    f32x4 acc[8];
#pragma unroll
    for (int dt = 0; dt < 8; ++dt) acc[dt] = zero;
    float lr[4] = {0.f, 0.f, 0.f, 0.f};

    __hip_bfloat16* pme = Plds + w * 640; // [16][40] bf16 per wave
    // per-lane mask base: row (ri0+g*4+r) stride 128 ull; word (jt>>8)*4 + (ln&3)
    const ull* bmw = bm + (size_t)(ri0 + g * 4) * 128 + (ln & 3);

    for (int tt = 0; tt < 32; ++tt) {
        const int t  = wj * 32 + tt;
        const int jt = t * 32;
        const int bit = ((jt >> 2) & 63) + (ln >> 2); // b0 at bit, b1 at bit+4

        // mask words (oldest in FIFO; consumed after QK)
        ull mw[4];
#pragma unroll
        for (int r = 0; r < 4; ++r)
            mw[r] = bmw[(size_t)r * 128 + (jt >> 8) * 4];

        // K fragments (L2)
        s16x8 kf[2][4];
#pragma unroll
        for (int jt2 = 0; jt2 < 2; ++jt2)
#pragma unroll
            for (int kt = 0; kt < 4; ++kt)
                kf[jt2][kt] = *(const s16x8*)(Kbf + (size_t)(jt + jt2 * 16 + ln) * DIM + kt * 32 + g * 8);

        // V fragments (newest in FIFO; consumed in PV, latency hidden by QK+softmax)
        s16x8 vf[8];
#pragma unroll
        for (int dt = 0; dt < 8; ++dt)
            vf[dt] = *(const s16x8*)(Vt + (size_t)(dt * 16 + ln) * MCOLS + jt + g * 8);

        // S = Q K^T
        f32x4 s0 = zero, s1 = zero;
#pragma unroll
        for (int kt = 0; kt < 4; ++kt) {
            s0 = __builtin_amdgcn_mfma_f32_16x16x32_bf16(qf[kt], kf[0][kt], s0, 0, 0, 0);
            s1 = __builtin_amdgcn_mfma_f32_16x16x32_bf16(qf[kt], kf[1][kt], s1, 0, 0, 0);
        }

        // p = adj ? exp(s) : 0
#pragma unroll
        for (int r = 0; r < 4; ++r) {
            float p0 = ((mw[r] >> bit) & 1)       ? __expf(s0[r]) : 0.f;
            float p1 = ((mw[r] >> (bit + 4)) & 1) ? __expf(s1[r]) : 0.f;
            lr[r] += p0 + p1;
            pme[(g * 4 + r) * 40 + ln]      = __float2bfloat16(p0);
            pme[(g * 4 + r) * 40 + 16 + ln] = __float2bfloat16(p1);
        }

        // PV (same-wave LDS RAW)
        s16x8 pf = *(const s16x8*)(pme + ln * 40 + g * 8);
#pragma unroll
        for (int dt = 0; dt < 8; ++dt)
            acc[dt] = __builtin_amdgcn_mfma_f32_16x16x32_bf16(pf, vf[dt], acc[dt], 0, 0, 0);
    }

    // row sums (within 16-lane group)
#pragma unroll
    for (int r = 0; r < 4; ++r) {
        lr[r] += __shfl_xor(lr[r], 1);
        lr[r] += __shfl_xor(lr[r], 2);
        lr[r] += __shfl_xor(lr[r], 4);
        lr[r] += __shfl_xor(lr[r], 8);
    }

    // ---- merge 8 j-slice partials per row group (plain sums) ----
#pragma unroll
    for (int rgo = 0; rgo < 2; ++rgo) {
        __syncthreads();
        if (rg == rgo) {
#pragma unroll
            for (int dt = 0; dt < 8; ++dt)
#pragma unroll
                for (int r = 0; r < 4; ++r)
                    Opart[(wj * 16 + g * 4 + r) * 128 + dt * 16 + ln] = acc[dt][r];
            if (ln == 0) {
#pragma unroll
                for (int r = 0; r < 4; ++r) Lpart[wj * 16 + g * 4 + r] = lr[r];
            }
        }
        __syncthreads();
        const int row = tid >> 6;          // 0..15
        const int c2  = (tid & 63) * 2;    // 0..126
        float L = 0.f;
#pragma unroll
        for (int p = 0; p < 8; ++p) L += Lpart[p * 16 + row];
        float o0 = 0.f, o1 = 0.f;
#pragma unroll
        for (int p = 0; p < 8; ++p) {
            const float* op = Opart + (p * 16 + row) * 128 + c2;
            o0 += op[0];
            o1 += op[1];
        }
        float inv = 1.0f / fmaxf(L, 1e-37f);
        float2 ov = {o0 * inv, o1 * inv};
        *(float2*)(out + (size_t)(i0 + rgo * 16 + row) * DIM + c2) = ov;
    }
}

extern "C" void kernel_launch(void* const* d_in, const int* in_sizes, int n_in,
                              void* d_out, int out_size, void* d_ws, size_t ws_size,
                              hipStream_t stream) {
    const float* xi   = (const float*)d_in[0];
    const float* xj   = (const float*)d_in[1];
    const int*   adj  = (const int*)d_in[2];
    const float* beta = (const float*)d_in[3];
    float* out = (float*)d_out;

    char* ws = (char*)d_ws;
    __hip_bfloat16* Qbf = (__hip_bfloat16*)ws;                                   // 2 MiB
    __hip_bfloat16* Kbf = (__hip_bfloat16*)(ws + (size_t)NROWS * DIM * 2);       // 2 MiB
    __hip_bfloat16* Vt  = (__hip_bfloat16*)(ws + 2 * (size_t)NROWS * DIM * 2);   // 2 MiB
    ull*            bm  = (ull*)(ws + 3 * (size_t)NROWS * DIM * 2);              // 8 MiB

    hipLaunchKernelGGL(pack_adj7, dim3(2048), dim3(256), 0, stream, adj, bm);
    hipLaunchKernelGGL(prep_scale_both, dim3(4096), dim3(256), 0, stream, xi, xj, beta, Qbf, Kbf);
    hipLaunchKernelGGL(prep_vt, dim3(128, 2), dim3(256), 0, stream, xj, Vt);
    hipLaunchKernelGGL(flash7, dim3(NROWS / BI), dim3(1024), 0, stream, Qbf, Kbf, Vt, bm, out);
}

// Round 8
// 136.963 us; speedup vs baseline: 2.1648x; 2.1648x over previous
//
#include <hip/hip_runtime.h>
#include <hip/hip_bf16.h>

typedef float f32x4 __attribute__((ext_vector_type(4)));
typedef short s16x8 __attribute__((ext_vector_type(8)));
typedef unsigned long long ull;

#define NROWS 8192
#define MCOLS 8192
#define DIM   128
#define JSPLIT 16
#define JCHUNK 512   // cols per block
#define KVB    64    // cols per iteration
#define ITERS  8     // JCHUNK / KVB

typedef __attribute__((address_space(3))) unsigned int lds_u32;
typedef __attribute__((address_space(1))) unsigned int g_u32;

__device__ __forceinline__ void gl_lds16(const void* g, void* l) {
    __builtin_amdgcn_global_load_lds((const g_u32*)g, (lds_u32*)l, 16, 0, 0);
}

// ---- prep: per-row norm + bf16 convert for BOTH xi (scaled by beta) and xj ----
__global__ void prep_scale_both(const float* __restrict__ xi,
                                const float* __restrict__ xj,
                                const float* __restrict__ beta,
                                __hip_bfloat16* __restrict__ Qbf,
                                __hip_bfloat16* __restrict__ Kbf) {
    int gr = blockIdx.x * 4 + (threadIdx.x >> 6);
    int l = threadIdx.x & 63;
    const float* src;
    __hip_bfloat16* dst;
    int row;
    if (gr < NROWS) { row = gr;          src = xi; dst = Qbf; }
    else            { row = gr - NROWS;  src = xj; dst = Kbf; }
    const float* xr = src + (size_t)row * DIM;
    float x0 = xr[l], x1 = xr[l + 64];
    float ss = x0 * x0 + x1 * x1;
#pragma unroll
    for (int off = 32; off >= 1; off >>= 1) ss += __shfl_xor(ss, off);
    float s = 1.0f / sqrtf(ss);
    if (gr < NROWS) s *= beta[0];
    __hip_bfloat16* o = dst + (size_t)row * DIM;
    o[l]      = __float2bfloat16(x0 * s);
    o[l + 64] = __float2bfloat16(x1 * s);
}

// ---- prep: transpose xj -> Vt[d][j] bf16 (raw values) ----
__global__ void prep_vt(const float* __restrict__ xj, __hip_bfloat16* __restrict__ vt) {
    __shared__ float tile[64][65];
    int j0 = blockIdx.x * 64;
    int d0 = blockIdx.y * 64;
    int t = threadIdx.x; // 256
#pragma unroll
    for (int c = 0; c < 16; ++c) {
        int idx = t + 256 * c;
        int jr = idx >> 6, dc = idx & 63;
        tile[jr][dc] = xj[(size_t)(j0 + jr) * DIM + d0 + dc];
    }
    __syncthreads();
#pragma unroll
    for (int c = 0; c < 16; ++c) {
        int idx = t + 256 * c;
        int dr = idx >> 6, jc = idx & 63;
        vt[(size_t)(d0 + dr) * MCOLS + j0 + jc] = __float2bfloat16(tile[jc][dr]);
    }
}

// ---- pack adj -> PLAIN bit layout, grid-contiguous stream.
//      Window = 256 cols of one row (1KB). Lane reads cols k*64+lane (4 loads,
//      each 256B coalesced); ballot k -> word k plain: bm[row*128 + cw*4 + k]
//      bit l = adj[row][cw*256 + k*64 + l]. ----
__global__ __launch_bounds__(256) void pack_adj8(const int* __restrict__ adj,
                                                 ull* __restrict__ bm) {
    const int lane = threadIdx.x & 63;
    const int gw = (int)((blockIdx.x * 256 + threadIdx.x) >> 6); // 0..8191
#pragma unroll 2
    for (int s = 0; s < 32; ++s) {
        int win = gw + s * 8192;                 // 8MB contiguous per grid step
        const int* base = adj + (size_t)win * 256;
        int a0 = base[lane], a1 = base[64 + lane], a2 = base[128 + lane], a3 = base[192 + lane];
        ull b0 = __ballot(a0 != 0);
        ull b1 = __ballot(a1 != 0);
        ull b2 = __ballot(a2 != 0);
        ull b3 = __ballot(a3 != 0);
        if (lane < 4) {
            ull v = (lane == 0) ? b0 : ((lane == 1) ? b1 : ((lane == 2) ? b2 : b3));
            bm[(size_t)win * 4 + lane] = v;
        }
    }
}

// ---- flash8: m97-style structure. Per iter: global_load_lds-stage K/V tiles
//      (XOR-swizzled source, linear LDS dest), barrier, ds_read_b128 fragments,
//      MFMA, barrier. Mask bits from bm (L2/L3). Plain-sum softmax
//      (|score| <= beta < 1 -> p = adj ? exp(s) : 0, no max tracking).
//      Writes per-(jc) partial O and L; merge kernel reduces. ----
__global__ __launch_bounds__(256, 3) void flash8(const __hip_bfloat16* __restrict__ Qbf,
                                                 const __hip_bfloat16* __restrict__ Kbf,
                                                 const __hip_bfloat16* __restrict__ Vt,
                                                 const ull* __restrict__ bm,
                                                 float* __restrict__ Opart,
                                                 float* __restrict__ Lpart) {
    // LDS: K [64 j][128 d] = 16KB | V [128 d][64 j] = 16KB | P 4 waves x [16][72]
    __shared__ char smem[41984];
    unsigned short* Klds = (unsigned short*)smem;
    unsigned short* Vlds = (unsigned short*)(smem + 16384);
    __hip_bfloat16* Plds = (__hip_bfloat16*)(smem + 32768);

    const int tid  = threadIdx.x;
    const int w    = tid >> 6;
    const int lane = tid & 63;
    const int g    = lane >> 4;
    const int ln   = lane & 15;
    const int bid  = blockIdx.x;
    const int jc   = bid & (JSPLIT - 1);
    const int rt   = bid >> 4;
    const int wrow = rt * 64 + w * 16;   // this wave's 16 Q rows
    const int jbase = jc * JCHUNK;

    // Q fragments (A-operand), persistent in registers
    s16x8 qf[4];
#pragma unroll
    for (int kt = 0; kt < 4; ++kt)
        qf[kt] = *(const s16x8*)(Qbf + (size_t)(wrow + ln) * DIM + kt * 32 + g * 8);

    f32x4 zero = {0.f, 0.f, 0.f, 0.f};
    f32x4 acc[8];
#pragma unroll
    for (int dt = 0; dt < 8; ++dt) acc[dt] = zero;
    float lr[4] = {0.f, 0.f, 0.f, 0.f};

    __hip_bfloat16* pme = Plds + w * (16 * 72);

    for (int it = 0; it < ITERS; ++it) {
        const int jt = jbase + it * KVB;

        // ---- stage K tile: 1024 16B-units. unit S=(row j 0..63, u 0..15);
        //      src col-unit = u ^ (row&7) (involution; read applies same XOR)
#pragma unroll
        for (int p = 0; p < 4; ++p) {
            int S = p * 256 + tid;
            int row = S >> 4, u = S & 15;
            const char* src = (const char*)Kbf + (((size_t)(jt + row)) << 8) + ((u ^ (row & 7)) << 4);
            gl_lds16(src, smem + p * 4096 + w * 1024);
        }
        // ---- stage V tile: 1024 units. (row d 0..127, u 0..7)
#pragma unroll
        for (int p = 0; p < 4; ++p) {
            int S = p * 256 + tid;
            int row = S >> 3, u = S & 7;
            const char* src = (const char*)Vt + (((size_t)row) << 14) + (((size_t)jt) << 1) + ((u ^ (row & 7)) << 4);
            gl_lds16(src, smem + 16384 + p * 4096 + w * 1024);
        }
        __syncthreads();   // vmcnt(0) drain: LDS tiles valid

        // mask words (only vmem in flight now; consumed after QK)
        ull mw[4];
#pragma unroll
        for (int r = 0; r < 4; ++r)
            mw[r] = bm[(size_t)(wrow + g * 4 + r) * 128 + (jt >> 6)];

        // ---- QK: S[16 rows][64 cols] = Q (regs) x K^T (LDS)
        f32x4 s4[4];
#pragma unroll
        for (int ct = 0; ct < 4; ++ct) {
            f32x4 s = zero;
#pragma unroll
            for (int kt = 0; kt < 4; ++kt) {
                int row = ct * 16 + ln;
                s16x8 kf = *(const s16x8*)(Klds + row * 128 + (((kt * 4 + g) ^ (ln & 7)) << 3));
                s = __builtin_amdgcn_mfma_f32_16x16x32_bf16(qf[kt], kf, s, 0, 0, 0);
            }
            s4[ct] = s;
        }

        // ---- softmax-lite: p = adj ? exp(s) : 0
#pragma unroll
        for (int r = 0; r < 4; ++r) {
#pragma unroll
            for (int ct = 0; ct < 4; ++ct) {
                float p = ((mw[r] >> (ct * 16 + ln)) & 1) ? __expf(s4[ct][r]) : 0.f;
                lr[r] += p;
                pme[(g * 4 + r) * 72 + ct * 16 + ln] = __float2bfloat16(p);
            }
        }

        // ---- PV: acc += P (LDS, A) x V^T (LDS, B)
#pragma unroll
        for (int kt2 = 0; kt2 < 2; ++kt2) {
            s16x8 pf = *(const s16x8*)(pme + ln * 72 + kt2 * 32 + g * 8);
#pragma unroll
            for (int dt = 0; dt < 8; ++dt) {
                int row = dt * 16 + ln;
                s16x8 vf = *(const s16x8*)(Vlds + row * 64 + (((kt2 * 4 + g) ^ (ln & 7)) << 3));
                acc[dt] = __builtin_amdgcn_mfma_f32_16x16x32_bf16(pf, vf, acc[dt], 0, 0, 0);
            }
        }
        __syncthreads();   // all waves done reading LDS before next stage
    }

    // row sums within 16-lane group
#pragma unroll
    for (int r = 0; r < 4; ++r) {
        lr[r] += __shfl_xor(lr[r], 1);
        lr[r] += __shfl_xor(lr[r], 2);
        lr[r] += __shfl_xor(lr[r], 4);
        lr[r] += __shfl_xor(lr[r], 8);
    }

    // ---- write partials (plain sums; merge kernel divides) ----
    float* ob = Opart + ((size_t)jc * NROWS + wrow + g * 4) * DIM;
#pragma unroll
    for (int r = 0; r < 4; ++r)
#pragma unroll
        for (int dt = 0; dt < 8; ++dt)
            ob[(size_t)r * DIM + dt * 16 + ln] = acc[dt][r];
    if (ln == 0) {
#pragma unroll
        for (int r = 0; r < 4; ++r)
            Lpart[(size_t)jc * NROWS + wrow + g * 4 + r] = lr[r];
    }
}

// ---- merge: out[row][d] = sum_jc Op / sum_jc L ----
__global__ __launch_bounds__(256) void merge8(const float* __restrict__ Opart,
                                              const float* __restrict__ Lpart,
                                              float* __restrict__ out) {
    int gid = blockIdx.x * 256 + threadIdx.x;   // 262144 threads
    int row = gid >> 5;
    int dq  = (gid & 31) * 4;
    float4 sum = {0.f, 0.f, 0.f, 0.f};
    float L = 0.f;
#pragma unroll
    for (int jc = 0; jc < JSPLIT; ++jc) {
        float4 v = *(const float4*)(Opart + ((size_t)jc * NROWS + row) * DIM + dq);
        sum.x += v.x; sum.y += v.y; sum.z += v.z; sum.w += v.w;
        L += Lpart[(size_t)jc * NROWS + row];
    }
    float inv = 1.0f / fmaxf(L, 1e-37f);
    float4 ov = {sum.x * inv, sum.y * inv, sum.z * inv, sum.w * inv};
    *(float4*)(out + (size_t)row * DIM + dq) = ov;
}

extern "C" void kernel_launch(void* const* d_in, const int* in_sizes, int n_in,
                              void* d_out, int out_size, void* d_ws, size_t ws_size,
                              hipStream_t stream) {
    const float* xi   = (const float*)d_in[0];
    const float* xj   = (const float*)d_in[1];
    const int*   adj  = (const int*)d_in[2];
    const float* beta = (const float*)d_in[3];
    float* out = (float*)d_out;

    char* ws = (char*)d_ws;
    __hip_bfloat16* Qbf = (__hip_bfloat16*)ws;                                    // 2 MiB
    __hip_bfloat16* Kbf = (__hip_bfloat16*)(ws + (size_t)NROWS * DIM * 2);        // 2 MiB
    __hip_bfloat16* Vt  = (__hip_bfloat16*)(ws + 2 * (size_t)NROWS * DIM * 2);    // 2 MiB
    ull*            bm  = (ull*)(ws + 3 * (size_t)NROWS * DIM * 2);               // 8 MiB
    float*          Op  = (float*)(ws + 3 * (size_t)NROWS * DIM * 2 + (size_t)NROWS * (MCOLS / 8)); // 64 MiB
    float*          Lp  = (float*)((char*)Op + (size_t)JSPLIT * NROWS * DIM * 4); // 512 KiB

    hipLaunchKernelGGL(pack_adj8, dim3(2048), dim3(256), 0, stream, adj, bm);
    hipLaunchKernelGGL(prep_scale_both, dim3(4096), dim3(256), 0, stream, xi, xj, beta, Qbf, Kbf);
    hipLaunchKernelGGL(prep_vt, dim3(128, 2), dim3(256), 0, stream, xj, Vt);
    hipLaunchKernelGGL(flash8, dim3(128 * JSPLIT), dim3(256), 0, stream, Qbf, Kbf, Vt, bm, Op, Lp);
    hipLaunchKernelGGL(merge8, dim3(1024), dim3(256), 0, stream, Op, Lp, out);
}

// Round 9
// 127.438 us; speedup vs baseline: 2.3266x; 1.0747x over previous
//
#include <hip/hip_runtime.h>
#include <hip/hip_bf16.h>

typedef float f32x4 __attribute__((ext_vector_type(4)));
typedef short s16x8 __attribute__((ext_vector_type(8)));
typedef unsigned long long ull;

#define NROWS 8192
#define MCOLS 8192
#define DIM   128
#define JSPLIT 8
#define JCHUNK 1024  // cols per block
#define KVB    64    // cols per iteration
#define ITERS  16    // JCHUNK / KVB

typedef __attribute__((address_space(3))) unsigned int lds_u32;
typedef __attribute__((address_space(1))) unsigned int g_u32;

__device__ __forceinline__ void gl_lds16(const void* g, void* l) {
    __builtin_amdgcn_global_load_lds((const g_u32*)g, (lds_u32*)l, 16, 0, 0);
}

// ---- fused prep: adj bit-pack (grid-contiguous stream, dominates) +
//      row-norm bf16 Q/K (hidden under stream) + Vt transpose (blocks<256) ----
__global__ __launch_bounds__(256) void prep_all(const float* __restrict__ xi,
                                                const float* __restrict__ xj,
                                                const float* __restrict__ beta,
                                                const int* __restrict__ adj,
                                                __hip_bfloat16* __restrict__ Qbf,
                                                __hip_bfloat16* __restrict__ Kbf,
                                                __hip_bfloat16* __restrict__ Vt,
                                                ull* __restrict__ bm) {
    __shared__ float tile[64][65];
    const int tid  = threadIdx.x;
    const int w    = tid >> 6;
    const int lane = tid & 63;

    // Part B: row norms, 8 rows per block (2 per wave)
    {
        float b = beta[0];
#pragma unroll
        for (int sub = 0; sub < 2; ++sub) {
            int gr = blockIdx.x * 8 + w * 2 + sub;   // 0..16383
            const float* src;
            __hip_bfloat16* dst;
            int row;
            if (gr < NROWS) { row = gr;          src = xi; dst = Qbf; }
            else            { row = gr - NROWS;  src = xj; dst = Kbf; }
            const float* xr = src + (size_t)row * DIM;
            float x0 = xr[lane], x1 = xr[lane + 64];
            float ss = x0 * x0 + x1 * x1;
#pragma unroll
            for (int off = 32; off >= 1; off >>= 1) ss += __shfl_xor(ss, off);
            float s = 1.0f / sqrtf(ss);
            if (gr < NROWS) s *= b;
            __hip_bfloat16* o = dst + (size_t)row * DIM;
            o[lane]      = __float2bfloat16(x0 * s);
            o[lane + 64] = __float2bfloat16(x1 * s);
        }
    }

    // Part C: Vt transpose (raw xj), one 64x64 tile for blocks < 256
    if (blockIdx.x < 256) {
        int j0 = (blockIdx.x & 127) * 64;
        int d0 = (blockIdx.x >> 7) * 64;
#pragma unroll
        for (int c = 0; c < 16; ++c) {
            int idx = tid + 256 * c;
            int jr = idx >> 6, dc = idx & 63;
            tile[jr][dc] = xj[(size_t)(j0 + jr) * DIM + d0 + dc];
        }
        __syncthreads();
#pragma unroll
        for (int c = 0; c < 16; ++c) {
            int idx = tid + 256 * c;
            int dr = idx >> 6, jc = idx & 63;
            Vt[(size_t)(d0 + dr) * MCOLS + j0 + jc] = __float2bfloat16(tile[jc][dr]);
        }
        __syncthreads();
    }

    // Part A: adj pack. Window = 256 cols of one row; 8MB contiguous per step.
    const int gw = (int)((blockIdx.x * 256 + tid) >> 6); // 0..8191
#pragma unroll 2
    for (int s = 0; s < 32; ++s) {
        int win = gw + s * 8192;
        const int* base = adj + (size_t)win * 256;
        int a0 = base[lane], a1 = base[64 + lane], a2 = base[128 + lane], a3 = base[192 + lane];
        ull b0 = __ballot(a0 != 0);
        ull b1 = __ballot(a1 != 0);
        ull b2 = __ballot(a2 != 0);
        ull b3 = __ballot(a3 != 0);
        if (lane < 4) {
            ull v = (lane == 0) ? b0 : ((lane == 1) ? b1 : ((lane == 2) ? b2 : b3));
            bm[(size_t)win * 4 + lane] = v;
        }
    }
}

// ---- flash9: 2-phase pipelined m97 structure. Per iter:
//      mask loads (oldest) -> STAGE(t+1 -> other buf) -> compute(t) -> barrier.
//      The barrier's vmcnt(0) drain overlaps the whole compute phase. ----
__global__ __launch_bounds__(256, 2) void flash9(const __hip_bfloat16* __restrict__ Qbf,
                                                 const __hip_bfloat16* __restrict__ Kbf,
                                                 const __hip_bfloat16* __restrict__ Vt,
                                                 const ull* __restrict__ bm,
                                                 float* __restrict__ Opart,
                                                 float* __restrict__ Lpart) {
    // LDS: buf0 {K 16K | V 16K} buf1 {K 16K | V 16K} | P 4x[16][72] = 9216
    __shared__ char smem[74752];
    __hip_bfloat16* Plds = (__hip_bfloat16*)(smem + 65536);

    const int tid  = threadIdx.x;
    const int w    = tid >> 6;
    const int lane = tid & 63;
    const int g    = lane >> 4;
    const int ln   = lane & 15;
    const int bid  = blockIdx.x;
    const int jc   = bid & (JSPLIT - 1);
    const int rt   = bid >> 3;
    const int wrow = rt * 64 + w * 16;
    const int jbase = jc * JCHUNK;

    s16x8 qf[4];
#pragma unroll
    for (int kt = 0; kt < 4; ++kt)
        qf[kt] = *(const s16x8*)(Qbf + (size_t)(wrow + ln) * DIM + kt * 32 + g * 8);

    f32x4 zero = {0.f, 0.f, 0.f, 0.f};
    f32x4 acc[8];
#pragma unroll
    for (int dt = 0; dt < 8; ++dt) acc[dt] = zero;
    float lr[4] = {0.f, 0.f, 0.f, 0.f};

    __hip_bfloat16* pme = Plds + w * (16 * 72);

    // stage K[64][128] + V[128][64] tiles for col jt into buffer b
    auto STAGE = [&](int jt, int b) {
        char* kb = smem + b * 32768;
        char* vb = kb + 16384;
#pragma unroll
        for (int p = 0; p < 4; ++p) {
            int S = p * 256 + tid;
            int row = S >> 4, u = S & 15;
            gl_lds16((const char*)Kbf + (((size_t)(jt + row)) << 8) + ((u ^ (row & 7)) << 4),
                     kb + p * 4096 + w * 1024);
        }
#pragma unroll
        for (int p = 0; p < 4; ++p) {
            int S = p * 256 + tid;
            int row = S >> 3, u = S & 7;
            gl_lds16((const char*)Vt + (((size_t)row) << 14) + (((size_t)jt) << 1) + ((u ^ (row & 7)) << 4),
                     vb + p * 4096 + w * 1024);
        }
    };

    STAGE(jbase, 0);
    __syncthreads();
    int cur = 0;

    for (int it = 0; it < ITERS; ++it) {
        const int jt = jbase + it * KVB;

        // mask words first (oldest in FIFO -> their wait leaves STAGE in flight)
        ull mw[4];
#pragma unroll
        for (int r = 0; r < 4; ++r)
            mw[r] = bm[(size_t)(wrow + g * 4 + r) * 128 + (jt >> 6)];
        __builtin_amdgcn_sched_barrier(0);

        // prefetch next tile into the other buffer
        STAGE(jbase + ((it + 1) & (ITERS - 1)) * KVB, cur ^ 1);

        unsigned short* Klds = (unsigned short*)(smem + cur * 32768);
        unsigned short* Vlds = (unsigned short*)(smem + cur * 32768 + 16384);

        // QK: S[16 rows][64 cols]
        f32x4 s4[4];
#pragma unroll
        for (int ct = 0; ct < 4; ++ct) {
            f32x4 s = zero;
#pragma unroll
            for (int kt = 0; kt < 4; ++kt) {
                int row = ct * 16 + ln;
                s16x8 kf = *(const s16x8*)(Klds + row * 128 + (((kt * 4 + g) ^ (ln & 7)) << 3));
                s = __builtin_amdgcn_mfma_f32_16x16x32_bf16(qf[kt], kf, s, 0, 0, 0);
            }
            s4[ct] = s;
        }

        // softmax-lite: p = adj ? exp(s) : 0  (|score| <= beta < 1)
#pragma unroll
        for (int r = 0; r < 4; ++r) {
#pragma unroll
            for (int ct = 0; ct < 4; ++ct) {
                float p = ((mw[r] >> (ct * 16 + ln)) & 1) ? __expf(s4[ct][r]) : 0.f;
                lr[r] += p;
                pme[(g * 4 + r) * 72 + ct * 16 + ln] = __float2bfloat16(p);
            }
        }

        // PV: acc += P x V^T
#pragma unroll
        for (int kt2 = 0; kt2 < 2; ++kt2) {
            s16x8 pf = *(const s16x8*)(pme + ln * 72 + kt2 * 32 + g * 8);
#pragma unroll
            for (int dt = 0; dt < 8; ++dt) {
                int row = dt * 16 + ln;
                s16x8 vf = *(const s16x8*)(Vlds + row * 64 + (((kt2 * 4 + g) ^ (ln & 7)) << 3));
                acc[dt] = __builtin_amdgcn_mfma_f32_16x16x32_bf16(pf, vf, acc[dt], 0, 0, 0);
            }
        }

        __syncthreads();   // drains STAGE(t+1) (overlapped by compute above)
        cur ^= 1;
    }

    // row sums within 16-lane group
#pragma unroll
    for (int r = 0; r < 4; ++r) {
        lr[r] += __shfl_xor(lr[r], 1);
        lr[r] += __shfl_xor(lr[r], 2);
        lr[r] += __shfl_xor(lr[r], 4);
        lr[r] += __shfl_xor(lr[r], 8);
    }

    // write partials
    float* ob = Opart + ((size_t)jc * NROWS + wrow + g * 4) * DIM;
#pragma unroll
    for (int r = 0; r < 4; ++r)
#pragma unroll
        for (int dt = 0; dt < 8; ++dt)
            ob[(size_t)r * DIM + dt * 16 + ln] = acc[dt][r];
    if (ln == 0) {
#pragma unroll
        for (int r = 0; r < 4; ++r)
            Lpart[(size_t)jc * NROWS + wrow + g * 4 + r] = lr[r];
    }
}

// ---- merge: out[row][d] = sum_jc Op / sum_jc L ----
__global__ __launch_bounds__(256) void merge9(const float* __restrict__ Opart,
                                              const float* __restrict__ Lpart,
                                              float* __restrict__ out) {
    int gid = blockIdx.x * 256 + threadIdx.x;
    int row = gid >> 5;
    int dq  = (gid & 31) * 4;
    float4 sum = {0.f, 0.f, 0.f, 0.f};
    float L = 0.f;
#pragma unroll
    for (int jc = 0; jc < JSPLIT; ++jc) {
        float4 v = *(const float4*)(Opart + ((size_t)jc * NROWS + row) * DIM + dq);
        sum.x += v.x; sum.y += v.y; sum.z += v.z; sum.w += v.w;
        L += Lpart[(size_t)jc * NROWS + row];
    }
    float inv = 1.0f / fmaxf(L, 1e-37f);
    float4 ov = {sum.x * inv, sum.y * inv, sum.z * inv, sum.w * inv};
    *(float4*)(out + (size_t)row * DIM + dq) = ov;
}

extern "C" void kernel_launch(void* const* d_in, const int* in_sizes, int n_in,
                              void* d_out, int out_size, void* d_ws, size_t ws_size,
                              hipStream_t stream) {
    const float* xi   = (const float*)d_in[0];
    const float* xj   = (const float*)d_in[1];
    const int*   adj  = (const int*)d_in[2];
    const float* beta = (const float*)d_in[3];
    float* out = (float*)d_out;

    char* ws = (char*)d_ws;
    __hip_bfloat16* Qbf = (__hip_bfloat16*)ws;                                    // 2 MiB
    __hip_bfloat16* Kbf = (__hip_bfloat16*)(ws + (size_t)NROWS * DIM * 2);        // 2 MiB
    __hip_bfloat16* Vt  = (__hip_bfloat16*)(ws + 2 * (size_t)NROWS * DIM * 2);    // 2 MiB
    ull*            bm  = (ull*)(ws + 3 * (size_t)NROWS * DIM * 2);               // 8 MiB
    float*          Op  = (float*)(ws + 3 * (size_t)NROWS * DIM * 2 + (size_t)NROWS * (MCOLS / 8)); // 32 MiB
    float*          Lp  = (float*)((char*)Op + (size_t)JSPLIT * NROWS * DIM * 4); // 256 KiB

    hipLaunchKernelGGL(prep_all, dim3(2048), dim3(256), 0, stream, xi, xj, beta, adj, Qbf, Kbf, Vt, bm);
    hipLaunchKernelGGL(flash9, dim3(128 * JSPLIT), dim3(256), 0, stream, Qbf, Kbf, Vt, bm, Op, Lp);
    hipLaunchKernelGGL(merge9, dim3(1024), dim3(256), 0, stream, Op, Lp, out);
}

// Round 10
// 118.545 us; speedup vs baseline: 2.5011x; 1.0750x over previous
//
#include <hip/hip_runtime.h>
#include <hip/hip_bf16.h>

typedef float f32x4 __attribute__((ext_vector_type(4)));
typedef short s16x8 __attribute__((ext_vector_type(8)));
typedef unsigned long long ull;

#define NROWS 8192
#define MCOLS 8192
#define DIM   128
#define JSPLIT 8
#define JCHUNK 1024  // cols per block
#define KVB    64    // cols per iteration
#define ITERS  16    // JCHUNK / KVB

typedef __attribute__((address_space(3))) unsigned int lds_u32;
typedef __attribute__((address_space(1))) unsigned int g_u32;

__device__ __forceinline__ void gl_lds16(const void* g, void* l) {
    __builtin_amdgcn_global_load_lds((const g_u32*)g, (lds_u32*)l, 16, 0, 0);
}

// ---- fused prep: adj bit-pack (grid-contiguous stream, dominates) +
//      row-norm bf16 Q/K (hidden under stream) + Vt transpose (blocks<256) ----
__global__ __launch_bounds__(256) void prep_all(const float* __restrict__ xi,
                                                const float* __restrict__ xj,
                                                const float* __restrict__ beta,
                                                const int* __restrict__ adj,
                                                __hip_bfloat16* __restrict__ Qbf,
                                                __hip_bfloat16* __restrict__ Kbf,
                                                __hip_bfloat16* __restrict__ Vt,
                                                ull* __restrict__ bm) {
    __shared__ float tile[64][65];
    const int tid  = threadIdx.x;
    const int w    = tid >> 6;
    const int lane = tid & 63;

    // Part B: row norms, 8 rows per block (2 per wave)
    {
        float b = beta[0];
#pragma unroll
        for (int sub = 0; sub < 2; ++sub) {
            int gr = blockIdx.x * 8 + w * 2 + sub;   // 0..16383
            const float* src;
            __hip_bfloat16* dst;
            int row;
            if (gr < NROWS) { row = gr;          src = xi; dst = Qbf; }
            else            { row = gr - NROWS;  src = xj; dst = Kbf; }
            const float* xr = src + (size_t)row * DIM;
            float x0 = xr[lane], x1 = xr[lane + 64];
            float ss = x0 * x0 + x1 * x1;
#pragma unroll
            for (int off = 32; off >= 1; off >>= 1) ss += __shfl_xor(ss, off);
            float s = 1.0f / sqrtf(ss);
            if (gr < NROWS) s *= b;
            __hip_bfloat16* o = dst + (size_t)row * DIM;
            o[lane]      = __float2bfloat16(x0 * s);
            o[lane + 64] = __float2bfloat16(x1 * s);
        }
    }

    // Part C: Vt transpose (raw xj), one 64x64 tile for blocks < 256
    if (blockIdx.x < 256) {
        int j0 = (blockIdx.x & 127) * 64;
        int d0 = (blockIdx.x >> 7) * 64;
#pragma unroll
        for (int c = 0; c < 16; ++c) {
            int idx = tid + 256 * c;
            int jr = idx >> 6, dc = idx & 63;
            tile[jr][dc] = xj[(size_t)(j0 + jr) * DIM + d0 + dc];
        }
        __syncthreads();
#pragma unroll
        for (int c = 0; c < 16; ++c) {
            int idx = tid + 256 * c;
            int dr = idx >> 6, jc = idx & 63;
            Vt[(size_t)(d0 + dr) * MCOLS + j0 + jc] = __float2bfloat16(tile[jc][dr]);
        }
        __syncthreads();
    }

    // Part A: adj pack. Window = 256 cols of one row; 8MB contiguous per step.
    const int gw = (int)((blockIdx.x * 256 + tid) >> 6); // 0..8191
#pragma unroll 2
    for (int s = 0; s < 32; ++s) {
        int win = gw + s * 8192;
        const int* base = adj + (size_t)win * 256;
        int a0 = base[lane], a1 = base[64 + lane], a2 = base[128 + lane], a3 = base[192 + lane];
        ull b0 = __ballot(a0 != 0);
        ull b1 = __ballot(a1 != 0);
        ull b2 = __ballot(a2 != 0);
        ull b3 = __ballot(a3 != 0);
        if (lane < 4) {
            ull v = (lane == 0) ? b0 : ((lane == 1) ? b1 : ((lane == 2) ? b2 : b3));
            bm[(size_t)win * 4 + lane] = v;
        }
    }
}

// ---- flash10: 2-phase pipelined; each wave owns 32 rows (2x16-row tiles) so
//      every K/V ds_read_b128 fragment feeds 2 MFMAs -> LDS traffic halved
//      per row. P in XOR-swizzled [16][64] (no pad). LDS = exactly 80KB ->
//      2 blocks/CU. Plain-sum softmax (|score| <= beta < 1). ----
__global__ __launch_bounds__(256, 2) void flash10(const __hip_bfloat16* __restrict__ Qbf,
                                                  const __hip_bfloat16* __restrict__ Kbf,
                                                  const __hip_bfloat16* __restrict__ Vt,
                                                  const ull* __restrict__ bm,
                                                  float* __restrict__ Opart,
                                                  float* __restrict__ Lpart) {
    // LDS: K[2][64][128]bf16 @0 (2x16K) | V[2][128][64]bf16 @32768 (2x16K)
    //      P: 4 waves x 2 tiles x [16][64] swizzled @65536 (16K). Total 81920.
    __shared__ char smem[81920];

    const int tid  = threadIdx.x;
    const int w    = tid >> 6;
    const int lane = tid & 63;
    const int g    = lane >> 4;
    const int ln   = lane & 15;
    const int bid  = blockIdx.x;
    const int jc   = bid & (JSPLIT - 1);
    const int rt   = bid >> 3;            // 0..63
    const int wra  = rt * 128 + w * 32;   // wave's first row (2 tiles of 16)
    const int jbase = jc * JCHUNK;
    const int lx   = ln & 7;              // lane XOR for swizzled units

    // Q fragments for both row tiles
    s16x8 qf[2][4];
#pragma unroll
    for (int ti = 0; ti < 2; ++ti)
#pragma unroll
        for (int kt = 0; kt < 4; ++kt)
            qf[ti][kt] = *(const s16x8*)(Qbf + (size_t)(wra + ti * 16 + ln) * DIM + kt * 32 + g * 8);

    f32x4 zero = {0.f, 0.f, 0.f, 0.f};
    f32x4 acc[2][8];
#pragma unroll
    for (int ti = 0; ti < 2; ++ti)
#pragma unroll
        for (int dt = 0; dt < 8; ++dt) acc[ti][dt] = zero;
    float lr[2][4] = {{0.f, 0.f, 0.f, 0.f}, {0.f, 0.f, 0.f, 0.f}};

    char* pw = smem + 65536 + w * 4096;   // this wave's P (2 tiles x 2KB)

    auto STAGE = [&](int jt, int b) {
        char* kb = smem + b * 16384;
        char* vb = smem + 32768 + b * 16384;
#pragma unroll
        for (int p = 0; p < 4; ++p) {
            int S = p * 256 + tid;
            int row = S >> 4, u = S & 15;
            gl_lds16((const char*)Kbf + (((size_t)(jt + row)) << 8) + ((u ^ (row & 7)) << 4),
                     kb + p * 4096 + w * 1024);
        }
#pragma unroll
        for (int p = 0; p < 4; ++p) {
            int S = p * 256 + tid;
            int row = S >> 3, u = S & 7;
            gl_lds16((const char*)Vt + (((size_t)row) << 14) + (((size_t)jt) << 1) + ((u ^ (row & 7)) << 4),
                     vb + p * 4096 + w * 1024);
        }
    };

    STAGE(jbase, 0);
    __syncthreads();
    int cur = 0;

    for (int it = 0; it < ITERS; ++it) {
        const int jt = jbase + it * KVB;

        // mask words (oldest in FIFO; 2 tiles x 4 rows)
        ull mw[2][4];
#pragma unroll
        for (int ti = 0; ti < 2; ++ti)
#pragma unroll
            for (int r = 0; r < 4; ++r)
                mw[ti][r] = bm[(size_t)(wra + ti * 16 + g * 4 + r) * 128 + (jt >> 6)];
        __builtin_amdgcn_sched_barrier(0);

        // prefetch next tile into the other buffer
        STAGE(jbase + ((it + 1) & (ITERS - 1)) * KVB, cur ^ 1);

        const char* kb = smem + cur * 16384;
        const char* vb = smem + 32768 + cur * 16384;

        // QK: each kf fragment feeds both row tiles
        f32x4 s4[2][4];
#pragma unroll
        for (int ti = 0; ti < 2; ++ti)
#pragma unroll
            for (int ct = 0; ct < 4; ++ct) s4[ti][ct] = zero;
#pragma unroll
        for (int ct = 0; ct < 4; ++ct)
#pragma unroll
            for (int kt = 0; kt < 4; ++kt) {
                s16x8 kf = *(const s16x8*)(kb + (ct * 16 + ln) * 256 + (((kt * 4 + g) ^ lx) << 4));
                s4[0][ct] = __builtin_amdgcn_mfma_f32_16x16x32_bf16(qf[0][kt], kf, s4[0][ct], 0, 0, 0);
                s4[1][ct] = __builtin_amdgcn_mfma_f32_16x16x32_bf16(qf[1][kt], kf, s4[1][ct], 0, 0, 0);
            }

        // softmax-lite: p = adj ? exp(s) : 0; P -> swizzled LDS
#pragma unroll
        for (int ti = 0; ti < 2; ++ti)
#pragma unroll
            for (int r = 0; r < 4; ++r) {
                const int row = g * 4 + r;
                const int rs = row & 7;
#pragma unroll
                for (int ct = 0; ct < 4; ++ct) {
                    float p = ((mw[ti][r] >> (ct * 16 + ln)) & 1) ? __expf(s4[ti][ct][r]) : 0.f;
                    lr[ti][r] += p;
                    *(__hip_bfloat16*)(pw + ti * 2048 + row * 128 +
                                       (((ct * 2 + (ln >> 3)) ^ rs) << 4) + (ln & 7) * 2)
                        = __float2bfloat16(p);
                }
            }

        // PV: each vf fragment feeds both row tiles (same-wave LDS RAW on P)
#pragma unroll
        for (int kt2 = 0; kt2 < 2; ++kt2) {
            const int uo = ((kt2 * 4 + g) ^ lx) << 4;
            s16x8 pf0 = *(const s16x8*)(pw + ln * 128 + uo);
            s16x8 pf1 = *(const s16x8*)(pw + 2048 + ln * 128 + uo);
#pragma unroll
            for (int dt = 0; dt < 8; ++dt) {
                s16x8 vf = *(const s16x8*)(vb + (dt * 16 + ln) * 128 + uo);
                acc[0][dt] = __builtin_amdgcn_mfma_f32_16x16x32_bf16(pf0, vf, acc[0][dt], 0, 0, 0);
                acc[1][dt] = __builtin_amdgcn_mfma_f32_16x16x32_bf16(pf1, vf, acc[1][dt], 0, 0, 0);
            }
        }

        __syncthreads();   // drains STAGE(t+1) (overlapped by compute above)
        cur ^= 1;
    }

    // row sums within 16-lane group
#pragma unroll
    for (int ti = 0; ti < 2; ++ti)
#pragma unroll
        for (int r = 0; r < 4; ++r) {
            lr[ti][r] += __shfl_xor(lr[ti][r], 1);
            lr[ti][r] += __shfl_xor(lr[ti][r], 2);
            lr[ti][r] += __shfl_xor(lr[ti][r], 4);
            lr[ti][r] += __shfl_xor(lr[ti][r], 8);
        }

    // write partials
#pragma unroll
    for (int ti = 0; ti < 2; ++ti) {
        float* ob = Opart + ((size_t)jc * NROWS + wra + ti * 16 + g * 4) * DIM;
#pragma unroll
        for (int r = 0; r < 4; ++r)
#pragma unroll
            for (int dt = 0; dt < 8; ++dt)
                ob[(size_t)r * DIM + dt * 16 + ln] = acc[ti][dt][r];
        if (ln == 0) {
#pragma unroll
            for (int r = 0; r < 4; ++r)
                Lpart[(size_t)jc * NROWS + wra + ti * 16 + g * 4 + r] = lr[ti][r];
        }
    }
}

// ---- merge: out[row][d] = sum_jc Op / sum_jc L ----
__global__ __launch_bounds__(256) void merge10(const float* __restrict__ Opart,
                                               const float* __restrict__ Lpart,
                                               float* __restrict__ out) {
    int gid = blockIdx.x * 256 + threadIdx.x;
    int row = gid >> 5;
    int dq  = (gid & 31) * 4;
    float4 sum = {0.f, 0.f, 0.f, 0.f};
    float L = 0.f;
#pragma unroll
    for (int jc = 0; jc < JSPLIT; ++jc) {
        float4 v = *(const float4*)(Opart + ((size_t)jc * NROWS + row) * DIM + dq);
        sum.x += v.x; sum.y += v.y; sum.z += v.z; sum.w += v.w;
        L += Lpart[(size_t)jc * NROWS + row];
    }
    float inv = 1.0f / fmaxf(L, 1e-37f);
    float4 ov = {sum.x * inv, sum.y * inv, sum.z * inv, sum.w * inv};
    *(float4*)(out + (size_t)row * DIM + dq) = ov;
}

extern "C" void kernel_launch(void* const* d_in, const int* in_sizes, int n_in,
                              void* d_out, int out_size, void* d_ws, size_t ws_size,
                              hipStream_t stream) {
    const float* xi   = (const float*)d_in[0];
    const float* xj   = (const float*)d_in[1];
    const int*   adj  = (const int*)d_in[2];
    const float* beta = (const float*)d_in[3];
    float* out = (float*)d_out;

    char* ws = (char*)d_ws;
    __hip_bfloat16* Qbf = (__hip_bfloat16*)ws;                                    // 2 MiB
    __hip_bfloat16* Kbf = (__hip_bfloat16*)(ws + (size_t)NROWS * DIM * 2);        // 2 MiB
    __hip_bfloat16* Vt  = (__hip_bfloat16*)(ws + 2 * (size_t)NROWS * DIM * 2);    // 2 MiB
    ull*            bm  = (ull*)(ws + 3 * (size_t)NROWS * DIM * 2);               // 8 MiB
    float*          Op  = (float*)(ws + 3 * (size_t)NROWS * DIM * 2 + (size_t)NROWS * (MCOLS / 8)); // 32 MiB
    float*          Lp  = (float*)((char*)Op + (size_t)JSPLIT * NROWS * DIM * 4); // 256 KiB

    hipLaunchKernelGGL(prep_all, dim3(2048), dim3(256), 0, stream, xi, xj, beta, adj, Qbf, Kbf, Vt, bm);
    hipLaunchKernelGGL(flash10, dim3(64 * JSPLIT), dim3(256), 0, stream, Qbf, Kbf, Vt, bm, Op, Lp);
    hipLaunchKernelGGL(merge10, dim3(1024), dim3(256), 0, stream, Op, Lp, out);
}